// Round 10
// baseline (298.705 us; speedup 1.0000x reference)
//
#include <hip/hip_runtime.h>
#include <hip/hip_bf16.h>

// Winograd F(2x2,3x3) via bf16 MFMA, kq-split blocks + plane-contiguous output.
// x (8,64,128,128) f32, filt (64,64,3,3) f32 -> Y (8,64,126,126) f32
// Block = (n, kq: 16 k, band: 3 tt rows = 6 output rows, all 63 uu, all 64 c).
// Grid 672 = 8 n x 4 kq x 21 tb; blockIdx&7 = n -> all of an image on one XCD.
// 12 passes: 3 tt x 2 ch(32c) x 2 a-pairs; 8 ab planes per pass -> LDS 36.9 KB
// -> 4 blocks/CU (32 waves = HW cap).

#define T_TILES 63
#define HW 128
#define OW 126

typedef __attribute__((ext_vector_type(8))) short short8;   // 8 bf16
typedef __attribute__((ext_vector_type(4))) float f32x4;

static __device__ __forceinline__ unsigned int f2bf(float f) {
    unsigned int u = __float_as_uint(f);
    return (u + 0x7FFFu + ((u >> 16) & 1u)) >> 16;   // RNE bf16
}

static __device__ __forceinline__ unsigned int pkbf2(float lo, float hi) {
    __hip_bfloat162 t;
    t.x = __float2bfloat16(lo);
    t.y = __float2bfloat16(hi);
    unsigned int r;
    __builtin_memcpy(&r, &t, 4);
    return r;                                   // v_cvt_pk_bf16_f32
}

// U_frag layout (unchanged): frag[(ab*2+ch)*4+kq][lane 0..63][j 0..7] bf16 (128 KB)
// B-operand lane l holds B[c'=(l>>4)*8+j (+32*ch)][k=(l&15)+16*kq]
__global__ __launch_bounds__(256)
void filter_transform(const float* __restrict__ g, unsigned short* __restrict__ Uf) {
    int idx = blockIdx.x * 256 + threadIdx.x;   // k*64 + c
    if (idx >= 64 * 64) return;
    int k = idx >> 6, c = idx & 63;
    const float* gp = g + idx * 9;
    float g00 = gp[0], g01 = gp[1], g02 = gp[2];
    float g10 = gp[3], g11 = gp[4], g12 = gp[5];
    float g20 = gp[6], g21 = gp[7], g22 = gp[8];
    float w[4][3];
    w[0][0] = g00;                w[0][1] = g01;                w[0][2] = g02;
    w[1][0] = 0.5f*(g00+g10+g20); w[1][1] = 0.5f*(g01+g11+g21); w[1][2] = 0.5f*(g02+g12+g22);
    w[2][0] = 0.5f*(g00-g10+g20); w[2][1] = 0.5f*(g01-g11+g21); w[2][2] = 0.5f*(g02-g12+g22);
    w[3][0] = g20;                w[3][1] = g21;                w[3][2] = g22;

    int kq = k >> 4, kl = k & 15;
    int ch = c >> 5;
    int lane = kl + (((c & 31) >> 3) << 4);
    int j = c & 7;
    #pragma unroll
    for (int a = 0; a < 4; ++a) {
        float uv[4];
        uv[0] = w[a][0];
        uv[1] = 0.5f * (w[a][0] + w[a][1] + w[a][2]);
        uv[2] = 0.5f * (w[a][0] - w[a][1] + w[a][2]);
        uv[3] = w[a][2];
        #pragma unroll
        for (int b = 0; b < 4; ++b) {
            int ab = a * 4 + b;
            size_t off = ((size_t)((ab * 2 + ch) * 4 + kq) * 64 + lane) * 8 + j;
            Uf[off] = (unsigned short)f2bf(uv[b]);
        }
    }
}

#define VSTRIDE 72                    // bytes per tm row (64 data + 8 pad)
#define VPLANE  (64 * VSTRIDE)        // 4608 B per ab-plane; 8 planes = 36864 B
#define YSTRIDE 758                   // f32 words per k-plane in staging (8 planes)

__global__ __launch_bounds__(512, 8)
void winograd_main(const float* __restrict__ x, const unsigned short* __restrict__ Uf,
                   float* __restrict__ Y) {
    extern __shared__ __align__(16) char smem[];

    const int tid  = threadIdx.x;
    const int lane = tid & 63;
    const int wv   = tid >> 6;                 // 0..7

    const int n  = blockIdx.x & 7;             // XCD id (round-robin heuristic)
    const int r2 = blockIdx.x >> 3;
    const int kq = r2 & 3;
    const int tb = r2 >> 2;                    // 0..20  (6-row band)

    const int mt = wv >> 1;                    // 0..3 M-tile (16 uu each)
    const int ai = wv & 1;                     // a within the active pair

    const int kl = lane & 15;
    const int g4 = lane >> 4;

    f32x4 Yp[3][2][2];                          // [tt][p][q]
    #pragma unroll
    for (int t = 0; t < 3; ++t)
        #pragma unroll
        for (int p = 0; p < 2; ++p)
            #pragma unroll
            for (int q = 0; q < 2; ++q)
                Yp[t][p][q] = (f32x4){0.f, 0.f, 0.f, 0.f};

    // transform mapping: tm = uu tile (0..63), cg = c-group of 4 channels
    const int tm = lane;
    const int cg = wv;
    const bool tvalid = (tm < T_TILES);

    // A-fragment read base (within an ab plane)
    const int tmA   = mt * 16 + kl;
    const int abyte = tmA * VSTRIDE + g4 * 16;

    const short8* UfV = (const short8*)Uf;

    #pragma unroll
    for (int tt = 0; tt < 3; ++tt) {
        #pragma unroll
        for (int ch = 0; ch < 2; ++ch) {
            #pragma unroll
            for (int P = 0; P < 2; ++P) {       // a-pair: a in {2P, 2P+1}
                const int xrow0 = 6 * tb + 2 * tt + P;   // rows xrow0..xrow0+2
                // ---- transform: 8 ab planes, 64 tm x 32 c' (4 c/thread) ----
                #pragma unroll
                for (int hp = 0; hp < 2; ++hp) {
                    float vv[2][8];
                    #pragma unroll
                    for (int hh = 0; hh < 2; ++hh) {
                        #pragma unroll
                        for (int e = 0; e < 8; ++e) vv[hh][e] = 0.f;
                        if (tvalid) {
                            const int c = ch * 32 + cg * 4 + hp * 2 + hh;
                            const float* xp = x + (((size_t)(n * 64 + c)) * HW + xrow0) * HW + 2 * tm;
                            float ld[3][4];
                            #pragma unroll
                            for (int rr = 0; rr < 3; ++rr) {
                                float2 lo = *reinterpret_cast<const float2*>(xp + rr * HW);
                                float2 hi = *reinterpret_cast<const float2*>(xp + rr * HW + 2);
                                ld[rr][0] = lo.x; ld[rr][1] = lo.y;
                                ld[rr][2] = hi.x; ld[rr][3] = hi.y;
                            }
                            float wa[2][4];
                            #pragma unroll
                            for (int j = 0; j < 4; ++j) {
                                if (P == 0) {
                                    wa[0][j] = ld[0][j] - ld[2][j];   // a=0
                                    wa[1][j] = ld[1][j] + ld[2][j];   // a=1
                                } else {
                                    wa[0][j] = ld[1][j] - ld[0][j];   // a=2
                                    wa[1][j] = ld[0][j] - ld[2][j];   // a=3
                                }
                            }
                            #pragma unroll
                            for (int al = 0; al < 2; ++al) {
                                vv[hh][al*4+0] = wa[al][0] - wa[al][2];
                                vv[hh][al*4+1] = wa[al][1] + wa[al][2];
                                vv[hh][al*4+2] = wa[al][2] - wa[al][1];
                                vv[hh][al*4+3] = wa[al][1] - wa[al][3];
                            }
                        }
                    }
                    const int wb = tm * VSTRIDE + cg * 8 + hp * 4;
                    #pragma unroll
                    for (int e = 0; e < 8; ++e)
                        *reinterpret_cast<unsigned int*>(smem + e * VPLANE + wb) =
                            pkbf2(vv[0][e], vv[1][e]);
                }
                __syncthreads();

                // ---- GEMM: wave (mt, ai): a = 2P+ai, 4 b, 16 k ----
                const int a = 2 * P + ai;
                f32x4 acc[4];
                #pragma unroll
                for (int b = 0; b < 4; ++b) acc[b] = (f32x4){0.f, 0.f, 0.f, 0.f};
                #pragma unroll
                for (int b = 0; b < 4; ++b) {
                    const char* ap = smem + (ai * 4 + b) * VPLANE + abyte;
                    uint2 q0 = *reinterpret_cast<const uint2*>(ap);
                    uint2 q1 = *reinterpret_cast<const uint2*>(ap + 8);
                    uint4 t; t.x = q0.x; t.y = q0.y; t.z = q1.x; t.w = q1.y;
                    short8 Af = *reinterpret_cast<short8*>(&t);
                    short8 Bf = UfV[(size_t)(((a * 4 + b) * 2 + ch) * 4 + kq) * 64 + lane];
                    acc[b] = __builtin_amdgcn_mfma_f32_16x16x32_bf16(Af, Bf, acc[b], 0, 0, 0);
                }

                // ---- fold (linear in partial sums) ----
                f32x4 t0 = acc[0] + acc[1] + acc[2];
                f32x4 t1 = acc[1] - acc[2] - acc[3];
                if (a == 0) { Yp[tt][0][0] += t0; Yp[tt][0][1] += t1; }
                if (a == 1) { Yp[tt][0][0] += t0; Yp[tt][0][1] += t1;
                              Yp[tt][1][0] += t0; Yp[tt][1][1] += t1; }
                if (a == 2) { Yp[tt][0][0] += t0; Yp[tt][0][1] += t1;
                              Yp[tt][1][0] -= t0; Yp[tt][1][1] -= t1; }
                if (a == 3) { Yp[tt][1][0] -= t0; Yp[tt][1][1] -= t1; }
                __syncthreads();
            }
        }
    }

    // ---- store: 2 rounds of 8 k-planes; merge ai halves in LDS, then
    //      plane-contiguous float2 copy-out ----
    float* Ys = reinterpret_cast<float*>(smem);
    #pragma unroll
    for (int round = 0; round < 2; ++round) {
        __syncthreads();
        if (ai == 0 && (kl >> 3) == round) {
            #pragma unroll
            for (int tt = 0; tt < 3; ++tt)
                #pragma unroll
                for (int r = 0; r < 4; ++r) {
                    const int uu = mt * 16 + 4 * g4 + r;
                    if (uu < T_TILES) {
                        #pragma unroll
                        for (int p = 0; p < 2; ++p)
                            *reinterpret_cast<float2*>(
                                Ys + (kl & 7) * YSTRIDE + (2 * tt + p) * 126 + 2 * uu)
                                = make_float2(Yp[tt][p][0][r], Yp[tt][p][1][r]);
                    }
                }
        }
        __syncthreads();
        if (ai == 1 && (kl >> 3) == round) {
            #pragma unroll
            for (int tt = 0; tt < 3; ++tt)
                #pragma unroll
                for (int r = 0; r < 4; ++r) {
                    const int uu = mt * 16 + 4 * g4 + r;
                    if (uu < T_TILES) {
                        #pragma unroll
                        for (int p = 0; p < 2; ++p) {
                            float2* ptr = reinterpret_cast<float2*>(
                                Ys + (kl & 7) * YSTRIDE + (2 * tt + p) * 126 + 2 * uu);
                            float2 v = *ptr;
                            v.x += Yp[tt][p][0][r];
                            v.y += Yp[tt][p][1][r];
                            *ptr = v;
                        }
                    }
                }
        }
        __syncthreads();
        // copy out: 8 planes x 756 floats (6 rows x 126); wave wv owns one plane
        const float* src = Ys + wv * YSTRIDE;
        float* dst = Y + ((size_t)(n * 64 + kq * 16 + round * 8 + wv)) * (OW * OW) + 756 * tb;
        #pragma unroll
        for (int it = 0; it < 6; ++it) {
            int idx = it * 64 + lane;
            if (idx < 378) {
                float2 v = *reinterpret_cast<const float2*>(src + 2 * idx);
                *reinterpret_cast<float2*>(dst + 2 * idx) = v;
            }
        }
    }
}

extern "C" void kernel_launch(void* const* d_in, const int* in_sizes, int n_in,
                              void* d_out, int out_size, void* d_ws, size_t ws_size,
                              hipStream_t stream) {
    const float* x    = (const float*)d_in[0];
    const float* filt = (const float*)d_in[1];
    float* Y = (float*)d_out;
    unsigned short* Uf = (unsigned short*)d_ws;    // 128 KB bf16 U fragments

    filter_transform<<<16, 256, 0, stream>>>(filt, Uf);

    winograd_main<<<dim3(672), 512, 8 * VPLANE, stream>>>(x, Uf, Y);
}

// Round 11
// 117.479 us; speedup vs baseline: 2.5426x; 2.5426x over previous
//
#include <hip/hip_runtime.h>
#include <hip/hip_bf16.h>

// Winograd F(2x2,3x3) via bf16 MFMA, kq-split blocks + plane-contiguous output.
// x (8,64,128,128) f32, filt (64,64,3,3) f32 -> Y (8,64,126,126) f32
// Block = (n, kq: 16 k, band: 3 tt rows = 6 output rows, all 63 uu, all 64 c).
// Grid 672 = 8 n x 4 kq x 21 tb; blockIdx&7 = n -> all of an image on one XCD.
// 12 passes: 3 tt x 2 ch(32c) x 2 a-pairs; 8 ab planes per pass -> LDS 36.9 KB
// -> 4 blocks/CU (32 waves = HW cap). launch_bounds (512,4): VGPR cap 64 (no spill;
// (512,8) capped at 32 and spilled catastrophically -- R10 post-mortem).

#define T_TILES 63
#define HW 128
#define OW 126

typedef __attribute__((ext_vector_type(8))) short short8;   // 8 bf16
typedef __attribute__((ext_vector_type(4))) float f32x4;

static __device__ __forceinline__ unsigned int f2bf(float f) {
    unsigned int u = __float_as_uint(f);
    return (u + 0x7FFFu + ((u >> 16) & 1u)) >> 16;   // RNE bf16
}

static __device__ __forceinline__ unsigned int pkbf2(float lo, float hi) {
    __hip_bfloat162 t;
    t.x = __float2bfloat16(lo);
    t.y = __float2bfloat16(hi);
    unsigned int r;
    __builtin_memcpy(&r, &t, 4);
    return r;                                   // v_cvt_pk_bf16_f32
}

// U_frag layout (unchanged): frag[(ab*2+ch)*4+kq][lane 0..63][j 0..7] bf16 (128 KB)
// B-operand lane l holds B[c'=(l>>4)*8+j (+32*ch)][k=(l&15)+16*kq]
__global__ __launch_bounds__(256)
void filter_transform(const float* __restrict__ g, unsigned short* __restrict__ Uf) {
    int idx = blockIdx.x * 256 + threadIdx.x;   // k*64 + c
    if (idx >= 64 * 64) return;
    int k = idx >> 6, c = idx & 63;
    const float* gp = g + idx * 9;
    float g00 = gp[0], g01 = gp[1], g02 = gp[2];
    float g10 = gp[3], g11 = gp[4], g12 = gp[5];
    float g20 = gp[6], g21 = gp[7], g22 = gp[8];
    float w[4][3];
    w[0][0] = g00;                w[0][1] = g01;                w[0][2] = g02;
    w[1][0] = 0.5f*(g00+g10+g20); w[1][1] = 0.5f*(g01+g11+g21); w[1][2] = 0.5f*(g02+g12+g22);
    w[2][0] = 0.5f*(g00-g10+g20); w[2][1] = 0.5f*(g01-g11+g21); w[2][2] = 0.5f*(g02-g12+g22);
    w[3][0] = g20;                w[3][1] = g21;                w[3][2] = g22;

    int kq = k >> 4, kl = k & 15;
    int ch = c >> 5;
    int lane = kl + (((c & 31) >> 3) << 4);
    int j = c & 7;
    #pragma unroll
    for (int a = 0; a < 4; ++a) {
        float uv[4];
        uv[0] = w[a][0];
        uv[1] = 0.5f * (w[a][0] + w[a][1] + w[a][2]);
        uv[2] = 0.5f * (w[a][0] - w[a][1] + w[a][2]);
        uv[3] = w[a][2];
        #pragma unroll
        for (int b = 0; b < 4; ++b) {
            int ab = a * 4 + b;
            size_t off = ((size_t)((ab * 2 + ch) * 4 + kq) * 64 + lane) * 8 + j;
            Uf[off] = (unsigned short)f2bf(uv[b]);
        }
    }
}

#define VSTRIDE 72                    // bytes per tm row (64 data + 8 pad)
#define VPLANE  (64 * VSTRIDE)        // 4608 B per ab-plane; 8 planes = 36864 B
#define YSTRIDE 758                   // f32 words per k-plane in staging (8 planes)

__global__ __launch_bounds__(512, 4)
void winograd_main(const float* __restrict__ x, const unsigned short* __restrict__ Uf,
                   float* __restrict__ Y) {
    extern __shared__ __align__(16) char smem[];

    const int tid  = threadIdx.x;
    const int lane = tid & 63;
    const int wv   = tid >> 6;                 // 0..7

    const int n  = blockIdx.x & 7;             // XCD id (round-robin heuristic)
    const int r2 = blockIdx.x >> 3;
    const int kq = r2 & 3;
    const int tb = r2 >> 2;                    // 0..20  (6-row band)

    const int mt = wv >> 1;                    // 0..3 M-tile (16 uu each)
    const int ai = wv & 1;                     // a within the active pair

    const int kl = lane & 15;
    const int g4 = lane >> 4;

    f32x4 Yp[3][2][2];                          // [tt][p][q]
    #pragma unroll
    for (int t = 0; t < 3; ++t)
        #pragma unroll
        for (int p = 0; p < 2; ++p)
            #pragma unroll
            for (int q = 0; q < 2; ++q)
                Yp[t][p][q] = (f32x4){0.f, 0.f, 0.f, 0.f};

    // transform mapping: tm = uu tile (0..63), cg = c-group of 4 channels
    const int tm = lane;
    const int cg = wv;
    const bool tvalid = (tm < T_TILES);

    // A-fragment read base (within an ab plane)
    const int tmA   = mt * 16 + kl;
    const int abyte = tmA * VSTRIDE + g4 * 16;

    const short8* UfV = (const short8*)Uf;

    #pragma unroll
    for (int tt = 0; tt < 3; ++tt) {
        #pragma unroll
        for (int ch = 0; ch < 2; ++ch) {
            #pragma unroll
            for (int P = 0; P < 2; ++P) {       // a-pair: a in {2P, 2P+1}
                const int xrow0 = 6 * tb + 2 * tt + P;   // rows xrow0..xrow0+2
                // ---- transform: 8 ab planes, 64 tm x 32 c' (4 c/thread) ----
                #pragma unroll
                for (int hp = 0; hp < 2; ++hp) {
                    float vv[2][8];
                    #pragma unroll
                    for (int hh = 0; hh < 2; ++hh) {
                        #pragma unroll
                        for (int e = 0; e < 8; ++e) vv[hh][e] = 0.f;
                        if (tvalid) {
                            const int c = ch * 32 + cg * 4 + hp * 2 + hh;
                            const float* xp = x + (((size_t)(n * 64 + c)) * HW + xrow0) * HW + 2 * tm;
                            float ld[3][4];
                            #pragma unroll
                            for (int rr = 0; rr < 3; ++rr) {
                                float2 lo = *reinterpret_cast<const float2*>(xp + rr * HW);
                                float2 hi = *reinterpret_cast<const float2*>(xp + rr * HW + 2);
                                ld[rr][0] = lo.x; ld[rr][1] = lo.y;
                                ld[rr][2] = hi.x; ld[rr][3] = hi.y;
                            }
                            float wa[2][4];
                            #pragma unroll
                            for (int j = 0; j < 4; ++j) {
                                if (P == 0) {
                                    wa[0][j] = ld[0][j] - ld[2][j];   // a=0
                                    wa[1][j] = ld[1][j] + ld[2][j];   // a=1
                                } else {
                                    wa[0][j] = ld[1][j] - ld[0][j];   // a=2
                                    wa[1][j] = ld[0][j] - ld[2][j];   // a=3
                                }
                            }
                            #pragma unroll
                            for (int al = 0; al < 2; ++al) {
                                vv[hh][al*4+0] = wa[al][0] - wa[al][2];
                                vv[hh][al*4+1] = wa[al][1] + wa[al][2];
                                vv[hh][al*4+2] = wa[al][2] - wa[al][1];
                                vv[hh][al*4+3] = wa[al][1] - wa[al][3];
                            }
                        }
                    }
                    const int wb = tm * VSTRIDE + cg * 8 + hp * 4;
                    #pragma unroll
                    for (int e = 0; e < 8; ++e)
                        *reinterpret_cast<unsigned int*>(smem + e * VPLANE + wb) =
                            pkbf2(vv[0][e], vv[1][e]);
                }
                __syncthreads();

                // ---- GEMM: wave (mt, ai): a = 2P+ai, 4 b, 16 k ----
                const int a = 2 * P + ai;
                f32x4 acc[4];
                #pragma unroll
                for (int b = 0; b < 4; ++b) acc[b] = (f32x4){0.f, 0.f, 0.f, 0.f};
                #pragma unroll
                for (int b = 0; b < 4; ++b) {
                    const char* ap = smem + (ai * 4 + b) * VPLANE + abyte;
                    uint2 q0 = *reinterpret_cast<const uint2*>(ap);
                    uint2 q1 = *reinterpret_cast<const uint2*>(ap + 8);
                    uint4 t; t.x = q0.x; t.y = q0.y; t.z = q1.x; t.w = q1.y;
                    short8 Af = *reinterpret_cast<short8*>(&t);
                    short8 Bf = UfV[(size_t)(((a * 4 + b) * 2 + ch) * 4 + kq) * 64 + lane];
                    acc[b] = __builtin_amdgcn_mfma_f32_16x16x32_bf16(Af, Bf, acc[b], 0, 0, 0);
                }

                // ---- fold (linear in partial sums) ----
                f32x4 t0 = acc[0] + acc[1] + acc[2];
                f32x4 t1 = acc[1] - acc[2] - acc[3];
                if (a == 0) { Yp[tt][0][0] += t0; Yp[tt][0][1] += t1; }
                if (a == 1) { Yp[tt][0][0] += t0; Yp[tt][0][1] += t1;
                              Yp[tt][1][0] += t0; Yp[tt][1][1] += t1; }
                if (a == 2) { Yp[tt][0][0] += t0; Yp[tt][0][1] += t1;
                              Yp[tt][1][0] -= t0; Yp[tt][1][1] -= t1; }
                if (a == 3) { Yp[tt][1][0] -= t0; Yp[tt][1][1] -= t1; }
                __syncthreads();
            }
        }
    }

    // ---- store: 2 rounds of 8 k-planes; merge ai halves in LDS, then
    //      plane-contiguous float2 copy-out ----
    float* Ys = reinterpret_cast<float*>(smem);
    #pragma unroll
    for (int round = 0; round < 2; ++round) {
        __syncthreads();
        if (ai == 0 && (kl >> 3) == round) {
            #pragma unroll
            for (int tt = 0; tt < 3; ++tt)
                #pragma unroll
                for (int r = 0; r < 4; ++r) {
                    const int uu = mt * 16 + 4 * g4 + r;
                    if (uu < T_TILES) {
                        #pragma unroll
                        for (int p = 0; p < 2; ++p)
                            *reinterpret_cast<float2*>(
                                Ys + (kl & 7) * YSTRIDE + (2 * tt + p) * 126 + 2 * uu)
                                = make_float2(Yp[tt][p][0][r], Yp[tt][p][1][r]);
                    }
                }
        }
        __syncthreads();
        if (ai == 1 && (kl >> 3) == round) {
            #pragma unroll
            for (int tt = 0; tt < 3; ++tt)
                #pragma unroll
                for (int r = 0; r < 4; ++r) {
                    const int uu = mt * 16 + 4 * g4 + r;
                    if (uu < T_TILES) {
                        #pragma unroll
                        for (int p = 0; p < 2; ++p) {
                            float2* ptr = reinterpret_cast<float2*>(
                                Ys + (kl & 7) * YSTRIDE + (2 * tt + p) * 126 + 2 * uu);
                            float2 v = *ptr;
                            v.x += Yp[tt][p][0][r];
                            v.y += Yp[tt][p][1][r];
                            *ptr = v;
                        }
                    }
                }
        }
        __syncthreads();
        // copy out: 8 planes x 756 floats (6 rows x 126); wave wv owns one plane
        const float* src = Ys + wv * YSTRIDE;
        float* dst = Y + ((size_t)(n * 64 + kq * 16 + round * 8 + wv)) * (OW * OW) + 756 * tb;
        #pragma unroll
        for (int it = 0; it < 6; ++it) {
            int idx = it * 64 + lane;
            if (idx < 378) {
                float2 v = *reinterpret_cast<const float2*>(src + 2 * idx);
                *reinterpret_cast<float2*>(dst + 2 * idx) = v;
            }
        }
    }
}

extern "C" void kernel_launch(void* const* d_in, const int* in_sizes, int n_in,
                              void* d_out, int out_size, void* d_ws, size_t ws_size,
                              hipStream_t stream) {
    const float* x    = (const float*)d_in[0];
    const float* filt = (const float*)d_in[1];
    float* Y = (float*)d_out;
    unsigned short* Uf = (unsigned short*)d_ws;    // 128 KB bf16 U fragments

    filter_transform<<<16, 256, 0, stream>>>(filt, Uf);

    winograd_main<<<dim3(672), 512, 8 * VPLANE, stream>>>(x, Uf, Y);
}

// Round 12
// 60.215 us; speedup vs baseline: 4.9607x; 1.9510x over previous
//
#include <hip/hip_runtime.h>
#include <hip/hip_bf16.h>

// Winograd F(2x2,3x3) via bf16 MFMA, kq-split blocks + plane-contiguous output.
// x (8,64,128,128) f32, filt (64,64,3,3) f32 -> Y (8,64,126,126) f32
// Block = (n, kq: 16 k, band: 3 tt rows = 6 output rows, all 63 uu, all 64 c).
// Grid 672 = 8 n x 4 kq x 21 tb; blockIdx&7 = n -> all of an image on one XCD.
// 6 passes: 3 tt x 2 ch(32c); 16 ab planes per pass (73.7 KB LDS, 2 blocks/CU).
// T14 pipeline: next-pass x-loads issued into registers BEFORE current GEMM.
// NOTE: no min-waves in launch_bounds -- (512,4)/(512,8) made the allocator
// spill to hit the 64/32-VGPR tier (R10/R11 post-mortem: +140 MB scratch traffic).

#define T_TILES 63
#define HW 128
#define OW 126

typedef __attribute__((ext_vector_type(8))) short short8;   // 8 bf16
typedef __attribute__((ext_vector_type(4))) float f32x4;

static __device__ __forceinline__ unsigned int f2bf(float f) {
    unsigned int u = __float_as_uint(f);
    return (u + 0x7FFFu + ((u >> 16) & 1u)) >> 16;   // RNE bf16
}

static __device__ __forceinline__ unsigned int pkbf2(float lo, float hi) {
    __hip_bfloat162 t;
    t.x = __float2bfloat16(lo);
    t.y = __float2bfloat16(hi);
    unsigned int r;
    __builtin_memcpy(&r, &t, 4);
    return r;                                   // v_cvt_pk_bf16_f32
}

// U_frag layout (unchanged): frag[(ab*2+ch)*4+kq][lane 0..63][j 0..7] bf16 (128 KB)
// B-operand lane l holds B[c'=(l>>4)*8+j (+32*ch)][k=(l&15)+16*kq]
__global__ __launch_bounds__(256)
void filter_transform(const float* __restrict__ g, unsigned short* __restrict__ Uf) {
    int idx = blockIdx.x * 256 + threadIdx.x;   // k*64 + c
    if (idx >= 64 * 64) return;
    int k = idx >> 6, c = idx & 63;
    const float* gp = g + idx * 9;
    float g00 = gp[0], g01 = gp[1], g02 = gp[2];
    float g10 = gp[3], g11 = gp[4], g12 = gp[5];
    float g20 = gp[6], g21 = gp[7], g22 = gp[8];
    float w[4][3];
    w[0][0] = g00;                w[0][1] = g01;                w[0][2] = g02;
    w[1][0] = 0.5f*(g00+g10+g20); w[1][1] = 0.5f*(g01+g11+g21); w[1][2] = 0.5f*(g02+g12+g22);
    w[2][0] = 0.5f*(g00-g10+g20); w[2][1] = 0.5f*(g01-g11+g21); w[2][2] = 0.5f*(g02-g12+g22);
    w[3][0] = g20;                w[3][1] = g21;                w[3][2] = g22;

    int kq = k >> 4, kl = k & 15;
    int ch = c >> 5;
    int lane = kl + (((c & 31) >> 3) << 4);
    int j = c & 7;
    #pragma unroll
    for (int a = 0; a < 4; ++a) {
        float uv[4];
        uv[0] = w[a][0];
        uv[1] = 0.5f * (w[a][0] + w[a][1] + w[a][2]);
        uv[2] = 0.5f * (w[a][0] - w[a][1] + w[a][2]);
        uv[3] = w[a][2];
        #pragma unroll
        for (int b = 0; b < 4; ++b) {
            int ab = a * 4 + b;
            size_t off = ((size_t)((ab * 2 + ch) * 4 + kq) * 64 + lane) * 8 + j;
            Uf[off] = (unsigned short)f2bf(uv[b]);
        }
    }
}

#define VSTRIDE 72                    // bytes per tm row (64 data + 8 pad)
#define VPLANE  (64 * VSTRIDE)        // 4608 B per ab-plane; 16 planes = 73728 B
#define YSTRIDE 766                   // f32 words per k-plane in staging

static __device__ __forceinline__ void pfload(const float* __restrict__ xp,
                                              float2 (&pf)[4][2]) {
    #pragma unroll
    for (int rr = 0; rr < 4; ++rr) {
        pf[rr][0] = *reinterpret_cast<const float2*>(xp + rr * HW);
        pf[rr][1] = *reinterpret_cast<const float2*>(xp + rr * HW + 2);
    }
}

static __device__ __forceinline__ void trans1(const float2 (&pf)[4][2],
                                              float (&v)[16]) {
    float d[4][4];
    #pragma unroll
    for (int rr = 0; rr < 4; ++rr) {
        d[rr][0] = pf[rr][0].x; d[rr][1] = pf[rr][0].y;
        d[rr][2] = pf[rr][1].x; d[rr][3] = pf[rr][1].y;
    }
    float w[4][4];
    #pragma unroll
    for (int j = 0; j < 4; ++j) {
        w[0][j] = d[0][j] - d[2][j];
        w[1][j] = d[1][j] + d[2][j];
        w[2][j] = d[2][j] - d[1][j];
        w[3][j] = d[1][j] - d[3][j];
    }
    #pragma unroll
    for (int a = 0; a < 4; ++a) {
        v[a*4+0] = w[a][0] - w[a][2];
        v[a*4+1] = w[a][1] + w[a][2];
        v[a*4+2] = w[a][2] - w[a][1];
        v[a*4+3] = w[a][1] - w[a][3];
    }
}

__global__ __launch_bounds__(512)
void winograd_main(const float* __restrict__ x, const unsigned short* __restrict__ Uf,
                   float* __restrict__ Y) {
    extern __shared__ __align__(16) char smem[];

    const int tid  = threadIdx.x;
    const int lane = tid & 63;
    const int wv   = tid >> 6;                 // 0..7

    const int n  = blockIdx.x & 7;             // XCD id (round-robin heuristic)
    const int r2 = blockIdx.x >> 3;
    const int kq = r2 & 3;
    const int tb = r2 >> 2;                    // 0..20  (6-row band)

    const int mt = wv >> 1;                    // 0..3 M-tile (16 uu each)
    const int ai = wv & 1;                     // a-pair half: a in {2ai, 2ai+1}

    const int kl = lane & 15;
    const int g4 = lane >> 4;

    f32x4 Yp[3][2][2];                          // [tt][p][q]
    #pragma unroll
    for (int t = 0; t < 3; ++t)
        #pragma unroll
        for (int p = 0; p < 2; ++p)
            #pragma unroll
            for (int q = 0; q < 2; ++q)
                Yp[t][p][q] = (f32x4){0.f, 0.f, 0.f, 0.f};

    // transform mapping: tm = uu tile (0..63), cg = c-group of 4 channels.
    // tm=63 is padding: clamp its address to tile 0; the garbage lands in
    // C row 63 which is discarded by the uu<63 guards in the epilogue.
    const int tm  = lane;
    const int cg  = wv;
    const int tmc = (tm < T_TILES) ? tm : 0;

    // A-fragment read base (within an ab plane)
    const int tmA   = mt * 16 + kl;
    const int abyte = tmA * VSTRIDE + g4 * 16;

    const short8* UfV = (const short8*)Uf;

    auto xaddr = [&](int c, int row) -> const float* {
        return x + (((size_t)(n * 64 + c)) * HW + row) * HW + 2 * tmc;
    };

    float2 pfA[2][4][2], pfB[2][4][2];
    // prologue: issue pass(tt=0, ch=0) hp0 loads (channels cg*4+0, cg*4+1)
    pfload(xaddr(cg * 4 + 0, 6 * tb), pfA[0]);
    pfload(xaddr(cg * 4 + 1, 6 * tb), pfA[1]);

    #pragma unroll
    for (int tt = 0; tt < 3; ++tt) {
        #pragma unroll
        for (int ch = 0; ch < 2; ++ch) {
            const int xrow0 = 6 * tb + 2 * tt;
            const int cb    = ch * 32 + cg * 4;

            // issue hp1 loads (channels cb+2, cb+3) -- hide under hp0 compute
            pfload(xaddr(cb + 2, xrow0), pfB[0]);
            pfload(xaddr(cb + 3, xrow0), pfB[1]);

            // transform hp0 from prefetched regs (pure VALU)
            float v0[16], v1[16];
            trans1(pfA[0], v0);
            trans1(pfA[1], v1);
            {
                const int wb = tm * VSTRIDE + cg * 8 + 0;
                #pragma unroll
                for (int e = 0; e < 16; ++e)
                    *reinterpret_cast<unsigned int*>(smem + e * VPLANE + wb) =
                        pkbf2(v0[e], v1[e]);
            }
            // transform hp1
            trans1(pfB[0], v0);
            trans1(pfB[1], v1);
            {
                const int wb = tm * VSTRIDE + cg * 8 + 4;
                #pragma unroll
                for (int e = 0; e < 16; ++e)
                    *reinterpret_cast<unsigned int*>(smem + e * VPLANE + wb) =
                        pkbf2(v0[e], v1[e]);
            }
            __syncthreads();

            // T14: issue NEXT pass hp0 loads before GEMM (latency hides under it)
            if (!(tt == 2 && ch == 1)) {
                const int ntt  = (ch == 1) ? tt + 1 : tt;
                const int nch  = (ch == 1) ? 0 : 1;
                const int nrow = 6 * tb + 2 * ntt;
                const int ncb  = nch * 32 + cg * 4;
                pfload(xaddr(ncb + 0, nrow), pfA[0]);
                pfload(xaddr(ncb + 1, nrow), pfA[1]);
            }

            // ---- GEMM: wave (mt, ai): a in {2ai, 2ai+1}, 4 b, 16 k ----
            f32x4 acc[2][4];
            #pragma unroll
            for (int aa = 0; aa < 2; ++aa)
                #pragma unroll
                for (int b = 0; b < 4; ++b)
                    acc[aa][b] = (f32x4){0.f, 0.f, 0.f, 0.f};

            #pragma unroll
            for (int aa = 0; aa < 2; ++aa) {
                const int a = 2 * ai + aa;
                #pragma unroll
                for (int b = 0; b < 4; ++b) {
                    const char* ap = smem + (a * 4 + b) * VPLANE + abyte;
                    uint2 q0 = *reinterpret_cast<const uint2*>(ap);
                    uint2 q1 = *reinterpret_cast<const uint2*>(ap + 8);
                    uint4 t; t.x = q0.x; t.y = q0.y; t.z = q1.x; t.w = q1.y;
                    short8 Af = *reinterpret_cast<short8*>(&t);
                    short8 Bf = UfV[(size_t)(((a * 4 + b) * 2 + ch) * 4 + kq) * 64 + lane];
                    acc[aa][b] = __builtin_amdgcn_mfma_f32_16x16x32_bf16(
                        Af, Bf, acc[aa][b], 0, 0, 0);
                }
            }

            // ---- fold (linear in partial sums) ----
            #pragma unroll
            for (int aa = 0; aa < 2; ++aa) {
                const int a = 2 * ai + aa;
                f32x4 t0 = acc[aa][0] + acc[aa][1] + acc[aa][2];
                f32x4 t1 = acc[aa][1] - acc[aa][2] - acc[aa][3];
                if (a == 0) { Yp[tt][0][0] += t0; Yp[tt][0][1] += t1; }
                if (a == 1) { Yp[tt][0][0] += t0; Yp[tt][0][1] += t1;
                              Yp[tt][1][0] += t0; Yp[tt][1][1] += t1; }
                if (a == 2) { Yp[tt][0][0] += t0; Yp[tt][0][1] += t1;
                              Yp[tt][1][0] -= t0; Yp[tt][1][1] -= t1; }
                if (a == 3) { Yp[tt][1][0] -= t0; Yp[tt][1][1] -= t1; }
            }
            __syncthreads();
        }
    }

    // ---- store: merge ai halves in LDS, then plane-contiguous float2 copy ----
    float* Ys = reinterpret_cast<float*>(smem);
    if (ai == 0) {
        #pragma unroll
        for (int tt = 0; tt < 3; ++tt)
            #pragma unroll
            for (int r = 0; r < 4; ++r) {
                const int uu = mt * 16 + 4 * g4 + r;
                if (uu < T_TILES) {
                    #pragma unroll
                    for (int p = 0; p < 2; ++p)
                        *reinterpret_cast<float2*>(Ys + kl * YSTRIDE + (2 * tt + p) * 126 + 2 * uu)
                            = make_float2(Yp[tt][p][0][r], Yp[tt][p][1][r]);
                }
            }
    }
    __syncthreads();
    if (ai == 1) {
        #pragma unroll
        for (int tt = 0; tt < 3; ++tt)
            #pragma unroll
            for (int r = 0; r < 4; ++r) {
                const int uu = mt * 16 + 4 * g4 + r;
                if (uu < T_TILES) {
                    #pragma unroll
                    for (int p = 0; p < 2; ++p) {
                        float2* ptr = reinterpret_cast<float2*>(
                            Ys + kl * YSTRIDE + (2 * tt + p) * 126 + 2 * uu);
                        float2 v = *ptr;
                        v.x += Yp[tt][p][0][r];
                        v.y += Yp[tt][p][1][r];
                        *ptr = v;
                    }
                }
            }
    }
    __syncthreads();

    // copy out: 16 planes x 756 floats (6 rows x 126) as float2
    const int kp = tid >> 5;                    // 0..15
    const int lx = tid & 31;
    const float* src = Ys + kp * YSTRIDE;
    float* dst = Y + ((size_t)(n * 64 + kq * 16 + kp)) * (OW * OW) + 756 * tb;
    #pragma unroll
    for (int it = 0; it < 12; ++it) {
        int idx = it * 32 + lx;
        if (idx < 378) {
            float2 v = *reinterpret_cast<const float2*>(src + 2 * idx);
            *reinterpret_cast<float2*>(dst + 2 * idx) = v;
        }
    }
}

extern "C" void kernel_launch(void* const* d_in, const int* in_sizes, int n_in,
                              void* d_out, int out_size, void* d_ws, size_t ws_size,
                              hipStream_t stream) {
    const float* x    = (const float*)d_in[0];
    const float* filt = (const float*)d_in[1];
    float* Y = (float*)d_out;
    unsigned short* Uf = (unsigned short*)d_ws;    // 128 KB bf16 U fragments

    filter_transform<<<16, 256, 0, stream>>>(filt, Uf);

    winograd_main<<<dim3(672), 512, 16 * VPLANE, stream>>>(x, Uf, Y);
}

// Round 13
// 53.415 us; speedup vs baseline: 5.5921x; 1.1273x over previous
//
#include <hip/hip_runtime.h>
#include <hip/hip_bf16.h>

// Winograd F(2x2,3x3) via bf16 MFMA.
// x (8,64,128,128) f32, filt (64,64,3,3) f32 -> Y (8,64,126,126) f32
// Block = (n, kq: 16 k, ONE tt row = 2 output rows, all 63 uu, all 64 c).
// Grid 2016 = 8 n x (63 tt x 4 kq); blockIdx&7 = n -> image pinned to one XCD,
// kq-siblings adjacent in time -> x rows hit L2.
// 4 passes (rolled): 2 ch(32c) x 2 a-pairs; 8 ab-planes/pass -> LDS 36.9 KB.
// Targets 4 blocks/CU NATURALLY (small Yp, rolled loop); no min-waves bound
// (R10/R11: forcing the tier makes the allocator spill -> 150+ MB scratch).

#define T_TILES 63
#define HW 128
#define OW 126

typedef __attribute__((ext_vector_type(8))) short short8;   // 8 bf16
typedef __attribute__((ext_vector_type(4))) float f32x4;

static __device__ __forceinline__ unsigned int f2bf(float f) {
    unsigned int u = __float_as_uint(f);
    return (u + 0x7FFFu + ((u >> 16) & 1u)) >> 16;   // RNE bf16
}

static __device__ __forceinline__ unsigned int pkbf2(float lo, float hi) {
    __hip_bfloat162 t;
    t.x = __float2bfloat16(lo);
    t.y = __float2bfloat16(hi);
    unsigned int r;
    __builtin_memcpy(&r, &t, 4);
    return r;                                   // v_cvt_pk_bf16_f32
}

// U_frag layout (unchanged): frag[(ab*2+ch)*4+kq][lane 0..63][j 0..7] bf16 (128 KB)
// B-operand lane l holds B[c'=(l>>4)*8+j (+32*ch)][k=(l&15)+16*kq]
__global__ __launch_bounds__(256)
void filter_transform(const float* __restrict__ g, unsigned short* __restrict__ Uf) {
    int idx = blockIdx.x * 256 + threadIdx.x;   // k*64 + c
    if (idx >= 64 * 64) return;
    int k = idx >> 6, c = idx & 63;
    const float* gp = g + idx * 9;
    float g00 = gp[0], g01 = gp[1], g02 = gp[2];
    float g10 = gp[3], g11 = gp[4], g12 = gp[5];
    float g20 = gp[6], g21 = gp[7], g22 = gp[8];
    float w[4][3];
    w[0][0] = g00;                w[0][1] = g01;                w[0][2] = g02;
    w[1][0] = 0.5f*(g00+g10+g20); w[1][1] = 0.5f*(g01+g11+g21); w[1][2] = 0.5f*(g02+g12+g22);
    w[2][0] = 0.5f*(g00-g10+g20); w[2][1] = 0.5f*(g01-g11+g21); w[2][2] = 0.5f*(g02-g12+g22);
    w[3][0] = g20;                w[3][1] = g21;                w[3][2] = g22;

    int kq = k >> 4, kl = k & 15;
    int ch = c >> 5;
    int lane = kl + (((c & 31) >> 3) << 4);
    int j = c & 7;
    #pragma unroll
    for (int a = 0; a < 4; ++a) {
        float uv[4];
        uv[0] = w[a][0];
        uv[1] = 0.5f * (w[a][0] + w[a][1] + w[a][2]);
        uv[2] = 0.5f * (w[a][0] - w[a][1] + w[a][2]);
        uv[3] = w[a][2];
        #pragma unroll
        for (int b = 0; b < 4; ++b) {
            int ab = a * 4 + b;
            size_t off = ((size_t)((ab * 2 + ch) * 4 + kq) * 64 + lane) * 8 + j;
            Uf[off] = (unsigned short)f2bf(uv[b]);
        }
    }
}

#define VSTRIDE 72                    // bytes per tm row (64 data + 8 pad)
#define VPLANE  (64 * VSTRIDE)        // 4608 B per ab-plane; 8 planes = 36864 B
#define YSTRIDE 254                   // f32 words per k-plane in staging (252 data + 2)

__global__ __launch_bounds__(512)
void winograd_main(const float* __restrict__ x, const unsigned short* __restrict__ Uf,
                   float* __restrict__ Y) {
    __shared__ __align__(16) char smem[8 * VPLANE];   // 36864 B

    const int tid  = threadIdx.x;
    const int lane = tid & 63;
    const int wv   = tid >> 6;                 // 0..7

    const int n  = blockIdx.x & 7;             // XCD pin
    const int r2 = blockIdx.x >> 3;            // 0..251
    const int kq = r2 & 3;
    const int tb = r2 >> 2;                    // 0..62 (tt row)

    const int mt = wv >> 1;                    // 0..3 M-tile (16 uu each)
    const int ai = wv & 1;                     // a within the active pair

    const int kl = lane & 15;
    const int g4 = lane >> 4;

    f32x4 Yp[2][2];                             // [p][q]
    #pragma unroll
    for (int p = 0; p < 2; ++p)
        #pragma unroll
        for (int q = 0; q < 2; ++q)
            Yp[p][q] = (f32x4){0.f, 0.f, 0.f, 0.f};

    // transform mapping: tm = uu tile (0..63; 63 = pad -> clamp addr, output
    // lands in discarded C row 63), cg = c-group of 4 channels
    const int tm  = lane;
    const int cg  = wv;
    const int tmc = (tm < T_TILES) ? tm : 0;

    // A-fragment read base (within an ab plane)
    const int tmA   = mt * 16 + kl;
    const int abyte = tmA * VSTRIDE + g4 * 16;

    const short8* UfV = (const short8*)Uf;

    #pragma unroll 1
    for (int pass = 0; pass < 4; ++pass) {
        const int ch = pass >> 1;
        const int P  = pass & 1;                // a-pair: a in {2P, 2P+1}
        const int xrow0 = 2 * tb + P;           // rows xrow0..xrow0+2 (max 127)

        // ---- transform: 8 ab planes, 64 tm x 32 c' (4 c/thread) ----
        #pragma unroll
        for (int hp = 0; hp < 2; ++hp) {
            float vv[2][8];
            #pragma unroll
            for (int hh = 0; hh < 2; ++hh) {
                const int c = ch * 32 + cg * 4 + hp * 2 + hh;
                const float* xp = x + (((size_t)(n * 64 + c)) * HW + xrow0) * HW + 2 * tmc;
                float ld[3][4];
                #pragma unroll
                for (int rr = 0; rr < 3; ++rr) {
                    float2 lo = *reinterpret_cast<const float2*>(xp + rr * HW);
                    float2 hi = *reinterpret_cast<const float2*>(xp + rr * HW + 2);
                    ld[rr][0] = lo.x; ld[rr][1] = lo.y;
                    ld[rr][2] = hi.x; ld[rr][3] = hi.y;
                }
                float wa[2][4];
                #pragma unroll
                for (int j = 0; j < 4; ++j) {
                    if (P == 0) {
                        wa[0][j] = ld[0][j] - ld[2][j];   // a=0
                        wa[1][j] = ld[1][j] + ld[2][j];   // a=1
                    } else {
                        wa[0][j] = ld[1][j] - ld[0][j];   // a=2
                        wa[1][j] = ld[0][j] - ld[2][j];   // a=3
                    }
                }
                #pragma unroll
                for (int al = 0; al < 2; ++al) {
                    vv[hh][al*4+0] = wa[al][0] - wa[al][2];
                    vv[hh][al*4+1] = wa[al][1] + wa[al][2];
                    vv[hh][al*4+2] = wa[al][2] - wa[al][1];
                    vv[hh][al*4+3] = wa[al][1] - wa[al][3];
                }
            }
            const int wb = tm * VSTRIDE + cg * 8 + hp * 4;
            #pragma unroll
            for (int e = 0; e < 8; ++e)
                *reinterpret_cast<unsigned int*>(smem + e * VPLANE + wb) =
                    pkbf2(vv[0][e], vv[1][e]);
        }
        __syncthreads();

        // ---- GEMM: wave (mt, ai): a = 2P+ai, 4 b, 16 k ----
        const int a = 2 * P + ai;
        f32x4 acc[4];
        #pragma unroll
        for (int b = 0; b < 4; ++b) acc[b] = (f32x4){0.f, 0.f, 0.f, 0.f};
        #pragma unroll
        for (int b = 0; b < 4; ++b) {
            const char* ap = smem + (ai * 4 + b) * VPLANE + abyte;
            uint2 q0 = *reinterpret_cast<const uint2*>(ap);
            uint2 q1 = *reinterpret_cast<const uint2*>(ap + 8);
            uint4 t; t.x = q0.x; t.y = q0.y; t.z = q1.x; t.w = q1.y;
            short8 Af = *reinterpret_cast<short8*>(&t);
            short8 Bf = UfV[(size_t)(((a * 4 + b) * 2 + ch) * 4 + kq) * 64 + lane];
            acc[b] = __builtin_amdgcn_mfma_f32_16x16x32_bf16(Af, Bf, acc[b], 0, 0, 0);
        }

        // ---- fold (linear in partial sums) ----
        f32x4 t0 = acc[0] + acc[1] + acc[2];
        f32x4 t1 = acc[1] - acc[2] - acc[3];
        if (a == 0) { Yp[0][0] += t0; Yp[0][1] += t1; }
        if (a == 1) { Yp[0][0] += t0; Yp[0][1] += t1;
                      Yp[1][0] += t0; Yp[1][1] += t1; }
        if (a == 2) { Yp[0][0] += t0; Yp[0][1] += t1;
                      Yp[1][0] -= t0; Yp[1][1] -= t1; }
        if (a == 3) { Yp[1][0] -= t0; Yp[1][1] -= t1; }
        __syncthreads();
    }

    // ---- store: merge ai halves in LDS (16 planes x 2 rows x 126), then
    //      plane-contiguous copy-out (252 contiguous floats per plane) ----
    float* Ys = reinterpret_cast<float*>(smem);
    if (ai == 0) {
        #pragma unroll
        for (int r = 0; r < 4; ++r) {
            const int uu = mt * 16 + 4 * g4 + r;
            if (uu < T_TILES) {
                #pragma unroll
                for (int p = 0; p < 2; ++p)
                    *reinterpret_cast<float2*>(Ys + kl * YSTRIDE + p * 126 + 2 * uu)
                        = make_float2(Yp[p][0][r], Yp[p][1][r]);
            }
        }
    }
    __syncthreads();
    if (ai == 1) {
        #pragma unroll
        for (int r = 0; r < 4; ++r) {
            const int uu = mt * 16 + 4 * g4 + r;
            if (uu < T_TILES) {
                #pragma unroll
                for (int p = 0; p < 2; ++p) {
                    float2* ptr = reinterpret_cast<float2*>(
                        Ys + kl * YSTRIDE + p * 126 + 2 * uu);
                    float2 v = *ptr;
                    v.x += Yp[p][0][r];
                    v.y += Yp[p][1][r];
                    *ptr = v;
                }
            }
        }
    }
    __syncthreads();

    // copy out: wave wv handles planes wv, wv+8; 126 float2 per plane
    #pragma unroll
    for (int i = 0; i < 2; ++i) {
        const int kp = wv + 8 * i;
        const float* src = Ys + kp * YSTRIDE;
        float* dst = Y + ((size_t)(n * 64 + kq * 16 + kp)) * (OW * OW)
                       + (size_t)(2 * tb) * OW;
        #pragma unroll
        for (int j = 0; j < 2; ++j) {
            int idx = lane + 64 * j;
            if (idx < 126) {
                float2 v = *reinterpret_cast<const float2*>(src + 2 * idx);
                *reinterpret_cast<float2*>(dst + 2 * idx) = v;
            }
        }
    }
}

extern "C" void kernel_launch(void* const* d_in, const int* in_sizes, int n_in,
                              void* d_out, int out_size, void* d_ws, size_t ws_size,
                              hipStream_t stream) {
    const float* x    = (const float*)d_in[0];
    const float* filt = (const float*)d_in[1];
    float* Y = (float*)d_out;
    unsigned short* Uf = (unsigned short*)d_ws;    // 128 KB bf16 U fragments

    filter_transform<<<16, 256, 0, stream>>>(filt, Uf);

    winograd_main<<<dim3(2016), 512, 0, stream>>>(x, Uf, Y);
}